// Round 5
// baseline (259.746 us; speedup 1.0000x reference)
//
#include <hip/hip_runtime.h>
#include <hip/hip_bf16.h>

#define CIN 256
#define NV 4096
#define NHEAD 8
#define HD 32
#define NSPLIT 2
#define KSPAN (NV / NSPLIT)

typedef __attribute__((ext_vector_type(8))) short short8;
typedef __attribute__((ext_vector_type(4))) float f32x4;

static __device__ __forceinline__ unsigned short f2bf(float f) {
    union { float f; unsigned u; } v; v.f = f;
    unsigned r = v.u + 0x7fffu + ((v.u >> 16) & 1u);  // RNE
    return (unsigned short)(r >> 16);
}

// pack two fp32 -> packed bf16 pair (truncating): low half from x0, high from x1
static __device__ __forceinline__ unsigned pk_bf2(float x0, float x1) {
    return __builtin_amdgcn_perm(__float_as_uint(x1), __float_as_uint(x0),
                                 0x07060302u);
}

// ---------------------------------------------------------------------------
// Kernel 1: QKV projection + RoPE -> bf16 in MFMA-friendly layouts:
//   Q,K -> [h][n][c], V -> [c][n].  BK=32 (halved barrier count).
// grid (NV/64, CIN/64, 3), block 256.  blockIdx.z: 0=Q,1=K,2=V
// ---------------------------------------------------------------------------
__global__ __launch_bounds__(256) void qkv_proj(
    const float* __restrict__ x,
    const float* __restrict__ wq, const float* __restrict__ bq,
    const float* __restrict__ wk, const float* __restrict__ bk,
    const float* __restrict__ wv, const float* __restrict__ bv,
    unsigned short* __restrict__ Qbf, unsigned short* __restrict__ Kbf,
    unsigned short* __restrict__ Vbf)
{
    const int which = blockIdx.z;
    const float* W = (which == 0) ? wq : (which == 1) ? wk : wv;
    const float* B = (which == 0) ? bq : (which == 1) ? bk : bv;
    const float* X = x + (which == 0 ? 0 : (size_t)CIN * NV);

    const int n0 = blockIdx.x * 64;
    const int m0 = blockIdx.y * 64;
    const int t = threadIdx.x;
    const int tx = t & 15, ty = t >> 4;

    __shared__ float Wts[32][64];
    __shared__ float Xs[32][64];

    float acc[4][4] = {};

    for (int k0 = 0; k0 < CIN; k0 += 32) {
#pragma unroll
        for (int rep = 0; rep < 2; ++rep) {
            int row = t >> 2, c4 = (t & 3) * 4 + rep * 16;
            float4 w4 = *(const float4*)&W[(size_t)(m0 + row) * CIN + k0 + c4];
            Wts[c4 + 0][row] = w4.x;
            Wts[c4 + 1][row] = w4.y;
            Wts[c4 + 2][row] = w4.z;
            Wts[c4 + 3][row] = w4.w;
            int xr = (t >> 4) + rep * 16, xc = (t & 15) * 4;
            *(float4*)&Xs[xr][xc] =
                *(const float4*)&X[(size_t)(k0 + xr) * NV + n0 + xc];
        }
        __syncthreads();
#pragma unroll
        for (int kk = 0; kk < 32; ++kk) {
            float a[4], b[4];
            *(float4*)a = *(const float4*)&Wts[kk][ty * 4];
            *(float4*)b = *(const float4*)&Xs[kk][tx * 4];
#pragma unroll
            for (int i = 0; i < 4; ++i)
#pragma unroll
                for (int j = 0; j < 4; ++j) acc[i][j] += a[i] * b[j];
        }
        __syncthreads();
    }

    if (which == 2) {
#pragma unroll
        for (int i = 0; i < 4; ++i) {
            const int m = m0 + ty * 4 + i;
            const float bias = B[m];
            unsigned short pk[4];
#pragma unroll
            for (int j = 0; j < 4; ++j) pk[j] = f2bf(acc[i][j] + bias);
            *(uint2*)&Vbf[(size_t)m * NV + n0 + tx * 4] = *(uint2*)pk;
        }
    } else {
        unsigned short* dst = (which == 0) ? Qbf : Kbf;
        const int h = (m0 + ty * 4) >> 5;
        const int c0 = (ty * 4) & 31;
        float v[4][4];
#pragma unroll
        for (int i = 0; i < 4; ++i) {
            const int m = m0 + ty * 4 + i;
            const float bias = B[m];
            const int d = m & (HD - 1);
            const float invf =
                __powf(10000.0f, -(float)(d & 15) * (1.0f / 16.0f));
#pragma unroll
            for (int j = 0; j < 4; ++j) {
                const int n = n0 + tx * 4 + j;
                float pos = (float)n * (2.0f / 4095.0f) - 1.0f;
                float ang = pos * invf;
                v[i][j] = (acc[i][j] + bias) * ((d < 16) ? __sinf(ang) : __cosf(ang));
            }
        }
#pragma unroll
        for (int j = 0; j < 4; ++j) {
            const int n = n0 + tx * 4 + j;
            unsigned short pk[4];
#pragma unroll
            for (int i = 0; i < 4; ++i) pk[i] = f2bf(v[i][j]);
            *(uint2*)&dst[((size_t)h * NV + n) * HD + c0] = *(uint2*)pk;
        }
    }
}

// ---------------------------------------------------------------------------
// Kernel 2: flash-style attention, bf16 MFMA, split-K, REGISTER-RESIDENT P.
// Trick: compute S^T = K·Q^T (operand swap) so each lane holds one query row
// of P (keys in groups of 4). PV then uses a permuted-key K=32 MFMA: the
// A-frag is the lane's own packed P values; the V B-frag loads the SAME
// permuted keys as two 8B reads from Vbf[c][key]. No LDS at all.
// grid (NV/64, NHEAD, NSPLIT), block 256 (4 fully-independent waves).
// ---------------------------------------------------------------------------
__global__ __launch_bounds__(256) void attn_mfma(
    const unsigned short* __restrict__ Qbf,
    const unsigned short* __restrict__ Kbf,
    const unsigned short* __restrict__ Vbf,
    float* __restrict__ Opart, float* __restrict__ Lpart)
{
    const int h = blockIdx.y;
    const int q0 = blockIdx.x * 64;
    const int z = blockIdx.z;
    const int kbase = z * KSPAN;
    const int t = threadIdx.x;
    const int w = t >> 6;
    const int lane = t & 63;
    const int ln = lane & 15;
    const int quad = lane >> 4;

    // Q fragment (B-operand for S^T): B[k=quad*8+j][n=ln] = Q[q=ln][c=quad*8+j]
    const short8 qa = *(const short8*)
        &Qbf[((size_t)h * NV + q0 + w * 16 + ln) * HD + quad * 8];

    const unsigned short* Kh = Kbf + (size_t)h * NV * HD;
    const unsigned short* Vh = Vbf + (size_t)h * HD * NV;

    f32x4 oacc[2] = {};
    float lsum = 0.f;

    // K fragments (A-operand): A[m=ln][k=quad*8+j] = K[key=16ct+ln][c=...]
    short8 kf[4];
#pragma unroll
    for (int ct = 0; ct < 4; ++ct)
        kf[ct] = *(const short8*)
            &Kh[(size_t)(kbase + ct * 16 + ln) * HD + quad * 8];

    for (int kk = 0; kk < KSPAN; kk += 64) {
        const int kb = kbase + kk;
        const int kbn = kbase + ((kk + 64) & (KSPAN - 1));

        // prefetch V B-frags: for half h2, key group g: keys kb+32h2+16g+quad*4..+3
        uint2 vraw[2][2][2];  // [ctile][h2][g]
#pragma unroll
        for (int ctile = 0; ctile < 2; ++ctile)
#pragma unroll
            for (int h2 = 0; h2 < 2; ++h2)
#pragma unroll
                for (int g = 0; g < 2; ++g)
                    vraw[ctile][h2][g] = *(const uint2*)
                        &Vh[(size_t)(ctile * 16 + ln) * NV + kb + h2 * 32 +
                            g * 16 + quad * 4];

        // S^T strips: lane holds P[q=ln][key = 16ct + quad*4 + r]
        f32x4 s[4];
#pragma unroll
        for (int ct = 0; ct < 4; ++ct) {
            f32x4 z4 = {0.f, 0.f, 0.f, 0.f};
            s[ct] = __builtin_amdgcn_mfma_f32_16x16x32_bf16(kf[ct], qa, z4, 0, 0, 0);
        }

        // prefetch next K tile
        short8 kfn[4];
#pragma unroll
        for (int ct = 0; ct < 4; ++ct)
            kfn[ct] = *(const short8*)
                &Kh[(size_t)(kbn + ct * 16 + ln) * HD + quad * 8];

        // exp (fp32) + truncate to bf16; lsum accumulates the truncated value
        float p[4][4];
#pragma unroll
        for (int ct = 0; ct < 4; ++ct)
#pragma unroll
            for (int r = 0; r < 4; ++r) {
                float e = __expf(s[ct][r]);
                float te = __uint_as_float(__float_as_uint(e) & 0xffff0000u);
                p[ct][r] = e;            // pack truncates identically
                lsum += te;
            }

        // PV: for half h2, A-frag = packed P keys {32h2+quad*4+0..3, 32h2+16+quad*4+0..3}
#pragma unroll
        for (int h2 = 0; h2 < 2; ++h2) {
            short8 pa;
            unsigned* pau = (unsigned*)&pa;
            pau[0] = pk_bf2(p[2 * h2][0], p[2 * h2][1]);
            pau[1] = pk_bf2(p[2 * h2][2], p[2 * h2][3]);
            pau[2] = pk_bf2(p[2 * h2 + 1][0], p[2 * h2 + 1][1]);
            pau[3] = pk_bf2(p[2 * h2 + 1][2], p[2 * h2 + 1][3]);
#pragma unroll
            for (int ctile = 0; ctile < 2; ++ctile) {
                short8 vb;
                unsigned* vbu = (unsigned*)&vb;
                vbu[0] = vraw[ctile][h2][0].x;
                vbu[1] = vraw[ctile][h2][0].y;
                vbu[2] = vraw[ctile][h2][1].x;
                vbu[3] = vraw[ctile][h2][1].y;
                oacc[ctile] = __builtin_amdgcn_mfma_f32_16x16x32_bf16(
                    pa, vb, oacc[ctile], 0, 0, 0);
            }
        }

#pragma unroll
        for (int ct = 0; ct < 4; ++ct) kf[ct] = kfn[ct];
    }

    // row sum l[q=ln]: reduce across the 4 quads (lanes ln, ln+16, ln+32, ln+48)
    lsum += __shfl_xor(lsum, 16, 64);
    lsum += __shfl_xor(lsum, 32, 64);

    float* Oz = Opart + (size_t)z * CIN * NV;
    float* Lz = Lpart + (size_t)z * NHEAD * NV;

    if (quad == 0) Lz[(size_t)h * NV + q0 + w * 16 + ln] = lsum;

    // O C-layout: lane holds O[q = quad*4+r][c = ctile*16+ln] -> dwordx4 store
#pragma unroll
    for (int ctile = 0; ctile < 2; ++ctile) {
        *(f32x4*)&Oz[(size_t)(h * HD + ctile * 16 + ln) * NV + q0 + w * 16 +
                     quad * 4] = oacc[ctile];
    }
}

// ---------------------------------------------------------------------------
// Kernel 3: combine split-K partials + output projection (BK=32):
//   A = (O0+O1)/(l0+l1);  out = wo @ (A + qf) + bo
// ---------------------------------------------------------------------------
__global__ __launch_bounds__(256) void out_proj(
    const float* __restrict__ x,
    const float* __restrict__ Opart, const float* __restrict__ Lpart,
    const float* __restrict__ wo, const float* __restrict__ bo,
    float* __restrict__ out)
{
    const int n0 = blockIdx.x * 64;
    const int m0 = blockIdx.y * 64;
    const int t = threadIdx.x;
    const int tx = t & 15, ty = t >> 4;

    const float* O0 = Opart;
    const float* O1 = Opart + (size_t)CIN * NV;
    const float* L0 = Lpart;
    const float* L1 = Lpart + (size_t)NHEAD * NV;

    __shared__ float Wts[32][64];
    __shared__ float Xs[32][64];

    float acc[4][4] = {};

    for (int k0 = 0; k0 < CIN; k0 += 32) {
#pragma unroll
        for (int rep = 0; rep < 2; ++rep) {
            int row = t >> 2, c4 = (t & 3) * 4 + rep * 16;
            float4 w4 = *(const float4*)&wo[(size_t)(m0 + row) * CIN + k0 + c4];
            Wts[c4 + 0][row] = w4.x;
            Wts[c4 + 1][row] = w4.y;
            Wts[c4 + 2][row] = w4.z;
            Wts[c4 + 3][row] = w4.w;

            int xr = (t >> 4) + rep * 16, xc = (t & 15) * 4;
            const int ch = k0 + xr;
            const int hh = ch >> 5;
            size_t off = (size_t)ch * NV + n0 + xc;
            size_t loff = (size_t)hh * NV + n0 + xc;
            float4 o0 = *(const float4*)&O0[off];
            float4 o1 = *(const float4*)&O1[off];
            float4 l0 = *(const float4*)&L0[loff];
            float4 l1 = *(const float4*)&L1[loff];
            float4 q4 = *(const float4*)&x[off];
            float4 s4;
            s4.x = (o0.x + o1.x) * __builtin_amdgcn_rcpf(l0.x + l1.x) + q4.x;
            s4.y = (o0.y + o1.y) * __builtin_amdgcn_rcpf(l0.y + l1.y) + q4.y;
            s4.z = (o0.z + o1.z) * __builtin_amdgcn_rcpf(l0.z + l1.z) + q4.z;
            s4.w = (o0.w + o1.w) * __builtin_amdgcn_rcpf(l0.w + l1.w) + q4.w;
            *(float4*)&Xs[xr][xc] = s4;
        }
        __syncthreads();
#pragma unroll
        for (int kk = 0; kk < 32; ++kk) {
            float a[4], b[4];
            *(float4*)a = *(const float4*)&Wts[kk][ty * 4];
            *(float4*)b = *(const float4*)&Xs[kk][tx * 4];
#pragma unroll
            for (int i = 0; i < 4; ++i)
#pragma unroll
                for (int j = 0; j < 4; ++j) acc[i][j] += a[i] * b[j];
        }
        __syncthreads();
    }

#pragma unroll
    for (int i = 0; i < 4; ++i) {
        const int m = m0 + ty * 4 + i;
        const float bias = bo[m];
#pragma unroll
        for (int j = 0; j < 4; ++j) {
            out[(size_t)m * NV + n0 + tx * 4 + j] = acc[i][j] + bias;
        }
    }
}

// ---------------------------------------------------------------------------
extern "C" void kernel_launch(void* const* d_in, const int* in_sizes, int n_in,
                              void* d_out, int out_size, void* d_ws,
                              size_t ws_size, hipStream_t stream)
{
    const float* x  = (const float*)d_in[0];
    const float* wq = (const float*)d_in[1];
    const float* bq = (const float*)d_in[2];
    const float* wk = (const float*)d_in[3];
    const float* bk = (const float*)d_in[4];
    const float* wv = (const float*)d_in[5];
    const float* bv = (const float*)d_in[6];
    const float* wo = (const float*)d_in[7];
    const float* bo = (const float*)d_in[8];
    float* out = (float*)d_out;

    unsigned short* Qbf = (unsigned short*)d_ws;        // 2MB
    unsigned short* Kbf = Qbf + (size_t)CIN * NV;       // 2MB
    unsigned short* Vbf = Kbf + (size_t)CIN * NV;       // 2MB
    float* Opart = (float*)(Vbf + (size_t)CIN * NV);    // NSPLIT * 4MB
    float* Lpart = Opart + (size_t)NSPLIT * CIN * NV;   // NSPLIT * 128KB

    qkv_proj<<<dim3(NV / 64, CIN / 64, 3), 256, 0, stream>>>(
        x, wq, bq, wk, bk, wv, bv, Qbf, Kbf, Vbf);
    attn_mfma<<<dim3(NV / 64, NHEAD, NSPLIT), 256, 0, stream>>>(
        Qbf, Kbf, Vbf, Opart, Lpart);
    out_proj<<<dim3(NV / 64, 512 / 64), 256, 0, stream>>>(
        x, Opart, Lpart, wo, bo, out);
}

// Round 6
// 156.507 us; speedup vs baseline: 1.6596x; 1.6596x over previous
//
#include <hip/hip_runtime.h>
#include <hip/hip_bf16.h>

#define CIN 256
#define NV 4096
#define NHEAD 8
#define HD 32
#define NSPLIT 2
#define KSPAN (NV / NSPLIT)

typedef __attribute__((ext_vector_type(8))) short short8;
typedef __attribute__((ext_vector_type(4))) float f32x4;

static __device__ __forceinline__ unsigned short f2bf(float f) {
    union { float f; unsigned u; } v; v.f = f;
    unsigned r = v.u + 0x7fffu + ((v.u >> 16) & 1u);  // RNE
    return (unsigned short)(r >> 16);
}
// pack two fp32 -> packed bf16 pair (truncating)
static __device__ __forceinline__ unsigned pk_bf2(float x0, float x1) {
    return __builtin_amdgcn_perm(__float_as_uint(x1), __float_as_uint(x0),
                                 0x07060302u);
}

// ---------------------------------------------------------------------------
// Kernel A: convert all weights to bf16 (flat). Wb = Wq|Wk|Wv|Wo, 327680 elems.
// ---------------------------------------------------------------------------
__global__ __launch_bounds__(256) void conv_w(
    const float* __restrict__ wq, const float* __restrict__ wk,
    const float* __restrict__ wv, const float* __restrict__ wo,
    unsigned short* __restrict__ Wb)
{
    int i = (blockIdx.x * 256 + threadIdx.x) * 4;
    if (i >= 327680) return;
    const float* src;
    int off = i;
    if (i < 65536) { src = wq; }
    else if (i < 131072) { src = wk; off = i - 65536; }
    else if (i < 196608) { src = wv; off = i - 131072; }
    else { src = wo; off = i - 196608; }
    float4 v = *(const float4*)&src[off];
    unsigned short pk[4] = {f2bf(v.x), f2bf(v.y), f2bf(v.z), f2bf(v.w)};
    *(uint2*)&Wb[i] = *(uint2*)pk;
}

// ---------------------------------------------------------------------------
// Kernel B: transpose x (fp32 [512][4096]) -> Xt bf16 [4096][512]
// ---------------------------------------------------------------------------
__global__ __launch_bounds__(256) void xt_kernel(
    const float* __restrict__ x, unsigned short* __restrict__ Xt)
{
    const int n = blockIdx.x * 64 + (threadIdx.x & 63);
    const int c = blockIdx.y * 32 + (threadIdx.x >> 6) * 8;
    unsigned short pk[8];
#pragma unroll
    for (int i = 0; i < 8; ++i) pk[i] = f2bf(x[(size_t)(c + i) * NV + n]);
    *(uint4*)&Xt[(size_t)n * 512 + c] = *(uint4*)pk;
}

// ---------------------------------------------------------------------------
// Kernel C: QKV projection on bf16 MFMA + RoPE.
//   Q,K -> [h][n][c] bf16 ; V -> [c][n] bf16.  No LDS; 16B global frags.
// grid (NV/64, 4, 3), block 256 (wave w = 16 output rows).
// ---------------------------------------------------------------------------
__global__ __launch_bounds__(256) void qkv_mfma(
    const unsigned short* __restrict__ Wb, const unsigned short* __restrict__ Xt,
    const float* __restrict__ bq, const float* __restrict__ bk,
    const float* __restrict__ bv,
    unsigned short* __restrict__ Qbf, unsigned short* __restrict__ Kbf,
    unsigned short* __restrict__ Vbf)
{
    const int which = blockIdx.z;
    const unsigned short* W = Wb + (size_t)which * 65536;
    const float* B = (which == 0) ? bq : (which == 1) ? bk : bv;
    const int cbase = (which == 0) ? 0 : 256;

    const int n0 = blockIdx.x * 64;
    const int m0 = blockIdx.y * 64;
    const int t = threadIdx.x;
    const int w = t >> 6;
    const int lane = t & 63;
    const int ln = lane & 15;
    const int quad = lane >> 4;

    const unsigned short* Wrow = &W[(size_t)(m0 + w * 16 + ln) * 256 + quad * 8];

    f32x4 acc[4] = {};
    short8 a = *(const short8*)&Wrow[0];
    short8 b[4];
#pragma unroll
    for (int nt = 0; nt < 4; ++nt)
        b[nt] = *(const short8*)
            &Xt[(size_t)(n0 + nt * 16 + ln) * 512 + cbase + quad * 8];

    for (int k0 = 0; k0 < 256; k0 += 32) {
        const int kn = (k0 + 32 < 256) ? k0 + 32 : k0;
        short8 an = *(const short8*)&Wrow[kn];
        short8 bn[4];
#pragma unroll
        for (int nt = 0; nt < 4; ++nt)
            bn[nt] = *(const short8*)
                &Xt[(size_t)(n0 + nt * 16 + ln) * 512 + cbase + kn + quad * 8];
        if (which == 2) {
#pragma unroll
            for (int nt = 0; nt < 4; ++nt)
                acc[nt] = __builtin_amdgcn_mfma_f32_16x16x32_bf16(
                    b[nt], a, acc[nt], 0, 0, 0);
        } else {
#pragma unroll
            for (int nt = 0; nt < 4; ++nt)
                acc[nt] = __builtin_amdgcn_mfma_f32_16x16x32_bf16(
                    a, b[nt], acc[nt], 0, 0, 0);
        }
        a = an;
#pragma unroll
        for (int nt = 0; nt < 4; ++nt) b[nt] = bn[nt];
    }

    if (which == 2) {
        // lane holds V[n=n0+nt*16+quad*4+r][ch=m0+w*16+ln]
        const int ch = m0 + w * 16 + ln;
        const float bias = B[ch];
#pragma unroll
        for (int nt = 0; nt < 4; ++nt) {
            unsigned short pk[4];
#pragma unroll
            for (int r = 0; r < 4; ++r) pk[r] = f2bf(acc[nt][r] + bias);
            *(uint2*)&Vbf[(size_t)ch * NV + n0 + nt * 16 + quad * 4] =
                *(uint2*)pk;
        }
    } else {
        // lane holds D[m=m0+w*16+quad*4+r][n=n0+nt*16+ln]; RoPE + 4-ch pack
        unsigned short* dst = (which == 0) ? Qbf : Kbf;
        const int mb = m0 + w * 16 + quad * 4;
        const int h = mb >> 5;
        const int cb = mb & 31;  // 4-aligned -> whole quad on one side of 16
        float bias[4], invf[4];
#pragma unroll
        for (int r = 0; r < 4; ++r) {
            bias[r] = B[mb + r];
            invf[r] = __powf(10000.0f, -(float)((cb + r) & 15) * (1.0f / 16.0f));
        }
        const bool use_sin = (cb < 16);
#pragma unroll
        for (int nt = 0; nt < 4; ++nt) {
            const int n = n0 + nt * 16 + ln;
            const float pos = (float)n * (2.0f / 4095.0f) - 1.0f;
            unsigned short pk[4];
#pragma unroll
            for (int r = 0; r < 4; ++r) {
                float ang = pos * invf[r];
                float f = use_sin ? __sinf(ang) : __cosf(ang);
                pk[r] = f2bf((acc[nt][r] + bias[r]) * f);
            }
            *(uint2*)&dst[((size_t)h * NV + n) * HD + cb] = *(uint2*)pk;
        }
    }
}

// ---------------------------------------------------------------------------
// Kernel D: attention. bf16 MFMA, split-K, register-resident P,
// double-buffered async V staging (global_load_lds 16B), ONE barrier/iter.
// V LDS granule slot = gr ^ (c&7): b64 frag reads are 2-way (free).
// grid (NV/64, NHEAD, NSPLIT), block 256.
// ---------------------------------------------------------------------------
__global__ __launch_bounds__(256, 4) void attn_mfma(
    const unsigned short* __restrict__ Qbf,
    const unsigned short* __restrict__ Kbf,
    const unsigned short* __restrict__ Vbf,
    float* __restrict__ Opart, float* __restrict__ Lpart)
{
    const int h = blockIdx.y;
    const int q0 = blockIdx.x * 64;
    const int z = blockIdx.z;
    const int kbase = z * KSPAN;
    const int t = threadIdx.x;
    const int w = t >> 6;
    const int lane = t & 63;
    const int ln = lane & 15;
    const int quad = lane >> 4;

    __shared__ __align__(16) unsigned short Vs[2][2048];  // 2 x 4KB V tiles

    const short8 qa = *(const short8*)
        &Qbf[((size_t)h * NV + q0 + w * 16 + ln) * HD + quad * 8];

    const unsigned short* Kh = Kbf + (size_t)h * NV * HD;
    const unsigned short* Vh = Vbf + (size_t)h * HD * NV;

    const int c_st = (w << 3) + (lane >> 3);               // staged channel
    const int gr_st = (lane & 7) ^ (c_st & 7);             // swizzled granule
    const unsigned short* gsrc = Vh + (size_t)c_st * NV + gr_st * 8;
    unsigned short* lds0 = &Vs[0][(size_t)(w * 64 + lane) * 8];
    unsigned short* lds1 = &Vs[1][(size_t)(w * 64 + lane) * 8];

    f32x4 oacc[2] = {};
    float lsum = 0.f;

    __builtin_amdgcn_global_load_lds(
        (const __attribute__((address_space(1))) unsigned int*)(gsrc + kbase),
        (__attribute__((address_space(3))) unsigned int*)lds0, 16, 0, 0);
    short8 kf[4];
#pragma unroll
    for (int ct = 0; ct < 4; ++ct)
        kf[ct] = *(const short8*)
            &Kh[(size_t)(kbase + ct * 16 + ln) * HD + quad * 8];
    __syncthreads();

    for (int i = 0; i < KSPAN / 64; ++i) {
        const int kb = kbase + i * 64;
        const int buf = i & 1;

        if (i + 1 < KSPAN / 64) {
            __builtin_amdgcn_global_load_lds(
                (const __attribute__((address_space(1))) unsigned int*)(gsrc + kb + 64),
                (__attribute__((address_space(3))) unsigned int*)(buf ? lds0 : lds1),
                16, 0, 0);
        }
        const int kbn = kbase + (((i + 1) & (KSPAN / 64 - 1)) * 64);
        short8 kfn[4];
#pragma unroll
        for (int ct = 0; ct < 4; ++ct)
            kfn[ct] = *(const short8*)
                &Kh[(size_t)(kbn + ct * 16 + ln) * HD + quad * 8];

        // S^T: lane holds P[q=ln][key = kb + 16ct + quad*4 + r]
        f32x4 s[4];
#pragma unroll
        for (int ct = 0; ct < 4; ++ct) {
            f32x4 z4 = {0.f, 0.f, 0.f, 0.f};
            s[ct] = __builtin_amdgcn_mfma_f32_16x16x32_bf16(kf[ct], qa, z4,
                                                            0, 0, 0);
        }

        float p[4][4];
#pragma unroll
        for (int ct = 0; ct < 4; ++ct)
#pragma unroll
            for (int r = 0; r < 4; ++r) {
                float e = __expf(s[ct][r]);
                lsum += __uint_as_float(__float_as_uint(e) & 0xffff0000u);
                p[ct][r] = e;
            }

#pragma unroll
        for (int h2 = 0; h2 < 2; ++h2) {
            short8 pa;
            unsigned* pau = (unsigned*)&pa;
            pau[0] = pk_bf2(p[2 * h2][0], p[2 * h2][1]);
            pau[1] = pk_bf2(p[2 * h2][2], p[2 * h2][3]);
            pau[2] = pk_bf2(p[2 * h2 + 1][0], p[2 * h2 + 1][1]);
            pau[3] = pk_bf2(p[2 * h2 + 1][2], p[2 * h2 + 1][3]);
#pragma unroll
            for (int ctile = 0; ctile < 2; ++ctile) {
                const int cA = ctile * 16 + ln;
                short8 vb;
                unsigned* vbu = (unsigned*)&vb;
#pragma unroll
                for (int g = 0; g < 2; ++g) {
                    const int gr = h2 * 4 + g * 2 + (quad >> 1);
                    const int sg = gr ^ (ln & 7);
                    uint2 vv = *(const uint2*)
                        &Vs[buf][cA * 64 + sg * 8 + (quad & 1) * 4];
                    vbu[g * 2 + 0] = vv.x;
                    vbu[g * 2 + 1] = vv.y;
                }
                oacc[ctile] = __builtin_amdgcn_mfma_f32_16x16x32_bf16(
                    pa, vb, oacc[ctile], 0, 0, 0);
            }
        }

#pragma unroll
        for (int ct = 0; ct < 4; ++ct) kf[ct] = kfn[ct];
        __syncthreads();
    }

    lsum += __shfl_xor(lsum, 16, 64);
    lsum += __shfl_xor(lsum, 32, 64);

    float* Oz = Opart + (size_t)z * CIN * NV;
    float* Lz = Lpart + (size_t)z * NHEAD * NV;
    if (quad == 0) Lz[(size_t)h * NV + q0 + w * 16 + ln] = lsum;

#pragma unroll
    for (int ctile = 0; ctile < 2; ++ctile)
        *(f32x4*)&Oz[(size_t)(h * HD + ctile * 16 + ln) * NV + q0 + w * 16 +
                     quad * 4] = oacc[ctile];
}

// ---------------------------------------------------------------------------
// Kernel E: combine split-K partials -> Yt bf16 [n][256]
// ---------------------------------------------------------------------------
__global__ __launch_bounds__(256) void combine(
    const float* __restrict__ x, const float* __restrict__ Opart,
    const float* __restrict__ Lpart, unsigned short* __restrict__ Yt)
{
    const int n = blockIdx.x * 64 + (threadIdx.x & 63);
    const int c = blockIdx.y * 32 + (threadIdx.x >> 6) * 8;
    const int h = c >> 5;
    const float* O0 = Opart;
    const float* O1 = Opart + (size_t)CIN * NV;
    const float l = Lpart[(size_t)h * NV + n] +
                    Lpart[(size_t)(NHEAD + h) * NV + n];
    const float rl = __builtin_amdgcn_rcpf(l);
    unsigned short pk[8];
#pragma unroll
    for (int i = 0; i < 8; ++i) {
        size_t off = (size_t)(c + i) * NV + n;
        pk[i] = f2bf((O0[off] + O1[off]) * rl + x[off]);
    }
    *(uint4*)&Yt[(size_t)n * 256 + c] = *(uint4*)pk;
}

// ---------------------------------------------------------------------------
// Kernel F: output projection on bf16 MFMA: out = Wo @ Y + bo
// grid (NV/64, 8), block 256.
// ---------------------------------------------------------------------------
__global__ __launch_bounds__(256) void out_mfma(
    const unsigned short* __restrict__ Wob, const unsigned short* __restrict__ Yt,
    const float* __restrict__ bo, float* __restrict__ out)
{
    const int n0 = blockIdx.x * 64;
    const int m0 = blockIdx.y * 64;
    const int t = threadIdx.x;
    const int w = t >> 6;
    const int lane = t & 63;
    const int ln = lane & 15;
    const int quad = lane >> 4;

    const unsigned short* Wrow = &Wob[(size_t)(m0 + w * 16 + ln) * 256 + quad * 8];

    f32x4 acc[4] = {};
    short8 a = *(const short8*)&Wrow[0];
    short8 b[4];
#pragma unroll
    for (int nt = 0; nt < 4; ++nt)
        b[nt] = *(const short8*)&Yt[(size_t)(n0 + nt * 16 + ln) * 256 + quad * 8];

    for (int k0 = 0; k0 < 256; k0 += 32) {
        const int kn = (k0 + 32 < 256) ? k0 + 32 : k0;
        short8 an = *(const short8*)&Wrow[kn];
        short8 bn[4];
#pragma unroll
        for (int nt = 0; nt < 4; ++nt)
            bn[nt] = *(const short8*)
                &Yt[(size_t)(n0 + nt * 16 + ln) * 256 + kn + quad * 8];
#pragma unroll
        for (int nt = 0; nt < 4; ++nt)
            acc[nt] = __builtin_amdgcn_mfma_f32_16x16x32_bf16(a, b[nt], acc[nt],
                                                              0, 0, 0);
        a = an;
#pragma unroll
        for (int nt = 0; nt < 4; ++nt) b[nt] = bn[nt];
    }

    const int mb = m0 + w * 16 + quad * 4;
    float bias[4];
#pragma unroll
    for (int r = 0; r < 4; ++r) bias[r] = bo[mb + r];
#pragma unroll
    for (int nt = 0; nt < 4; ++nt)
#pragma unroll
        for (int r = 0; r < 4; ++r)
            out[(size_t)(mb + r) * NV + n0 + nt * 16 + ln] = acc[nt][r] + bias[r];
}

// ---------------------------------------------------------------------------
extern "C" void kernel_launch(void* const* d_in, const int* in_sizes, int n_in,
                              void* d_out, int out_size, void* d_ws,
                              size_t ws_size, hipStream_t stream)
{
    const float* x  = (const float*)d_in[0];
    const float* wq = (const float*)d_in[1];
    const float* bq = (const float*)d_in[2];
    const float* wk = (const float*)d_in[3];
    const float* bk = (const float*)d_in[4];
    const float* wv = (const float*)d_in[5];
    const float* bv = (const float*)d_in[6];
    const float* wo = (const float*)d_in[7];
    const float* bo = (const float*)d_in[8];
    float* out = (float*)d_out;

    unsigned short* Wb  = (unsigned short*)d_ws;             // Wq|Wk|Wv|Wo bf16
    unsigned short* Xt  = Wb + 327680;                       // [4096][512] bf16
    unsigned short* Qbf = Xt + (size_t)NV * 512;
    unsigned short* Kbf = Qbf + (size_t)CIN * NV;
    unsigned short* Vbf = Kbf + (size_t)CIN * NV;
    float* Lpart = (float*)(Vbf + (size_t)CIN * NV);
    unsigned short* Yt = (unsigned short*)(Lpart + 2 * (size_t)NHEAD * NV);
    float* Opart = out;  // d_out (8MB) = split-K scratch; fully overwritten
                         // by out_mfma at the end.

    conv_w<<<dim3(320), 256, 0, stream>>>(wq, wk, wv, wo, Wb);
    xt_kernel<<<dim3(64, 16), 256, 0, stream>>>(x, Xt);
    qkv_mfma<<<dim3(NV / 64, 4, 3), 256, 0, stream>>>(
        Wb, Xt, bq, bk, bv, Qbf, Kbf, Vbf);
    attn_mfma<<<dim3(NV / 64, NHEAD, NSPLIT), 256, 0, stream>>>(
        Qbf, Kbf, Vbf, Opart, Lpart);
    combine<<<dim3(64, 8), 256, 0, stream>>>(x, Opart, Lpart, Yt);
    out_mfma<<<dim3(NV / 64, 8), 256, 0, stream>>>(
        Wb + 196608, Yt, bo, out);
}

// Round 7
// 149.241 us; speedup vs baseline: 1.7404x; 1.0487x over previous
//
#include <hip/hip_runtime.h>
#include <hip/hip_bf16.h>

#define CIN 256
#define NV 4096
#define NHEAD 8
#define HD 32
#define NSPLIT 2
#define KSPAN (NV / NSPLIT)
#define LOG2E 1.44269504088896340736f

typedef __attribute__((ext_vector_type(8))) short short8;
typedef __attribute__((ext_vector_type(4))) float f32x4;

static __device__ __forceinline__ unsigned short f2bf(float f) {
    union { float f; unsigned u; } v; v.f = f;
    unsigned r = v.u + 0x7fffu + ((v.u >> 16) & 1u);  // RNE
    return (unsigned short)(r >> 16);
}
// pack two fp32 -> packed bf16 pair (truncating): lo from x0, hi from x1
static __device__ __forceinline__ unsigned pk_bf2(float x0, float x1) {
    return __builtin_amdgcn_perm(__float_as_uint(x1), __float_as_uint(x0),
                                 0x07060302u);
}

// ---------------------------------------------------------------------------
// Kernel 1: fused QKV projection. Stages x-transpose (bf16) in LDS per block,
// converts fp32 weights inline into A-fragments, bf16 MFMA, RoPE epilogue
// (Q additionally scaled by log2e so attention can use exp2).
//   Q,K -> [h][n][c] bf16 ; V -> [c][n] bf16
// grid (NV/64, 4, 3), block 256.
// ---------------------------------------------------------------------------
__global__ __launch_bounds__(256) void qkv_fused(
    const float* __restrict__ x,
    const float* __restrict__ wq, const float* __restrict__ bq,
    const float* __restrict__ wk, const float* __restrict__ bk,
    const float* __restrict__ wv, const float* __restrict__ bv,
    unsigned short* __restrict__ Qbf, unsigned short* __restrict__ Kbf,
    unsigned short* __restrict__ Vbf)
{
    const int which = blockIdx.z;
    const float* Wp = (which == 0) ? wq : (which == 1) ? wk : wv;
    const float* Bp = (which == 0) ? bq : (which == 1) ? bk : bv;
    const int cbase = (which == 0) ? 0 : CIN;

    const int n0 = blockIdx.x * 64;
    const int m0 = blockIdx.y * 64;
    const int t = threadIdx.x;

    __shared__ unsigned short Xs[64][264];  // [n][c], pitch 264 (16B mult)

    // stage: x [c][n] fp32 -> Xs [n][c] bf16 (coalesced reads, paired writes)
    {
        const int n = t & 63, cg = t >> 6;
#pragma unroll 4
        for (int cc = 0; cc < 64; cc += 2) {
            const int c = cg * 64 + cc;
            size_t off = (size_t)(cbase + c) * NV + n0 + n;
            *(unsigned*)&Xs[n][c] = pk_bf2(x[off], x[off + NV]);
        }
    }
    __syncthreads();

    const int w = t >> 6;
    const int lane = t & 63;
    const int ln = lane & 15;
    const int quad = lane >> 4;
    const int M = m0 + w * 16 + ln;

    f32x4 acc[4] = {};
    for (int k0 = 0; k0 < 256; k0 += 32) {
        float4 a0 = *(const float4*)&Wp[(size_t)M * 256 + k0 + quad * 8];
        float4 a1 = *(const float4*)&Wp[(size_t)M * 256 + k0 + quad * 8 + 4];
        short8 a;
        unsigned* au = (unsigned*)&a;
        au[0] = pk_bf2(a0.x, a0.y);
        au[1] = pk_bf2(a0.z, a0.w);
        au[2] = pk_bf2(a1.x, a1.y);
        au[3] = pk_bf2(a1.z, a1.w);
        short8 b[4];
#pragma unroll
        for (int nt = 0; nt < 4; ++nt)
            b[nt] = *(const short8*)&Xs[nt * 16 + ln][k0 + quad * 8];
        if (which == 2) {
#pragma unroll
            for (int nt = 0; nt < 4; ++nt)
                acc[nt] = __builtin_amdgcn_mfma_f32_16x16x32_bf16(
                    b[nt], a, acc[nt], 0, 0, 0);
        } else {
#pragma unroll
            for (int nt = 0; nt < 4; ++nt)
                acc[nt] = __builtin_amdgcn_mfma_f32_16x16x32_bf16(
                    a, b[nt], acc[nt], 0, 0, 0);
        }
    }

    if (which == 2) {
        // lane holds V[n=n0+nt*16+quad*4+r][ch=m0+w*16+ln]
        const int ch = m0 + w * 16 + ln;
        const float bias = Bp[ch];
#pragma unroll
        for (int nt = 0; nt < 4; ++nt) {
            unsigned short pk[4];
#pragma unroll
            for (int r = 0; r < 4; ++r) pk[r] = f2bf(acc[nt][r] + bias);
            *(uint2*)&Vbf[(size_t)ch * NV + n0 + nt * 16 + quad * 4] =
                *(uint2*)pk;
        }
    } else {
        // lane holds D[m=m0+w*16+quad*4+r][n=n0+nt*16+ln]; RoPE + 4-ch pack
        unsigned short* dst = (which == 0) ? Qbf : Kbf;
        const int mb = m0 + w * 16 + quad * 4;
        const int h = mb >> 5;
        const int cb = mb & 31;
        const float qscale = (which == 0) ? LOG2E : 1.0f;
        float bias[4], invf[4];
#pragma unroll
        for (int r = 0; r < 4; ++r) {
            bias[r] = Bp[mb + r];
            invf[r] = __powf(10000.0f, -(float)((cb + r) & 15) * (1.0f / 16.0f));
        }
        const bool use_sin = (cb < 16);
#pragma unroll
        for (int nt = 0; nt < 4; ++nt) {
            const int n = n0 + nt * 16 + ln;
            const float pos = (float)n * (2.0f / 4095.0f) - 1.0f;
            unsigned short pk[4];
#pragma unroll
            for (int r = 0; r < 4; ++r) {
                float ang = pos * invf[r];
                float f = (use_sin ? __sinf(ang) : __cosf(ang)) * qscale;
                pk[r] = f2bf((acc[nt][r] + bias[r]) * f);
            }
            *(uint2*)&dst[((size_t)h * NV + n) * HD + cb] = *(uint2*)pk;
        }
    }
}

// ---------------------------------------------------------------------------
// Kernel 2: attention. bf16 MFMA, split-K, register-resident P, async
// double-buffered V staging. Softmax denominators via ones-vector MFMA
// (identical weights to the PV numerator -> exact consistency; lacc rows
// align with oacc rows, no shuffles). Q pre-scaled by log2e -> exp2.
// grid (NV/64, NHEAD, NSPLIT), block 256.
// ---------------------------------------------------------------------------
__global__ __launch_bounds__(256, 4) void attn_mfma(
    const unsigned short* __restrict__ Qbf,
    const unsigned short* __restrict__ Kbf,
    const unsigned short* __restrict__ Vbf,
    float* __restrict__ Opart, float* __restrict__ Lpart)
{
    const int h = blockIdx.y;
    const int q0 = blockIdx.x * 64;
    const int z = blockIdx.z;
    const int kbase = z * KSPAN;
    const int t = threadIdx.x;
    const int w = t >> 6;
    const int lane = t & 63;
    const int ln = lane & 15;
    const int quad = lane >> 4;

    __shared__ __align__(16) unsigned short Vs[2][2048];  // 2 x 4KB V tiles

    const short8 qa = *(const short8*)
        &Qbf[((size_t)h * NV + q0 + w * 16 + ln) * HD + quad * 8];

    const unsigned short* Kh = Kbf + (size_t)h * NV * HD;
    const unsigned short* Vh = Vbf + (size_t)h * HD * NV;

    const int c_st = (w << 3) + (lane >> 3);
    const int gr_st = (lane & 7) ^ (c_st & 7);
    const unsigned short* gsrc = Vh + (size_t)c_st * NV + gr_st * 8;
    unsigned short* lds0 = &Vs[0][(size_t)(w * 64 + lane) * 8];
    unsigned short* lds1 = &Vs[1][(size_t)(w * 64 + lane) * 8];

    f32x4 oacc[2] = {};
    f32x4 lacc = {};
    const short vone = (short)0x3F80;
    const short8 vones = {vone, vone, vone, vone, vone, vone, vone, vone};

    __builtin_amdgcn_global_load_lds(
        (const __attribute__((address_space(1))) unsigned int*)(gsrc + kbase),
        (__attribute__((address_space(3))) unsigned int*)lds0, 16, 0, 0);
    short8 kf[4];
#pragma unroll
    for (int ct = 0; ct < 4; ++ct)
        kf[ct] = *(const short8*)
            &Kh[(size_t)(kbase + ct * 16 + ln) * HD + quad * 8];
    __syncthreads();

    for (int i = 0; i < KSPAN / 64; ++i) {
        const int kb = kbase + i * 64;
        const int buf = i & 1;

        if (i + 1 < KSPAN / 64) {
            __builtin_amdgcn_global_load_lds(
                (const __attribute__((address_space(1))) unsigned int*)(gsrc + kb + 64),
                (__attribute__((address_space(3))) unsigned int*)(buf ? lds0 : lds1),
                16, 0, 0);
        }
        const int kbn = kbase + (((i + 1) & (KSPAN / 64 - 1)) * 64);
        short8 kfn[4];
#pragma unroll
        for (int ct = 0; ct < 4; ++ct)
            kfn[ct] = *(const short8*)
                &Kh[(size_t)(kbn + ct * 16 + ln) * HD + quad * 8];

        // S^T: lane holds S'[q=ln][key = kb + 16ct + quad*4 + r] (log2-scaled)
        f32x4 s[4];
#pragma unroll
        for (int ct = 0; ct < 4; ++ct) {
            f32x4 z4 = {0.f, 0.f, 0.f, 0.f};
            s[ct] = __builtin_amdgcn_mfma_f32_16x16x32_bf16(kf[ct], qa, z4,
                                                            0, 0, 0);
        }

        float p[4][4];
#pragma unroll
        for (int ct = 0; ct < 4; ++ct)
#pragma unroll
            for (int r = 0; r < 4; ++r) p[ct][r] = exp2f(s[ct][r]);

#pragma unroll
        for (int h2 = 0; h2 < 2; ++h2) {
            short8 pa;
            unsigned* pau = (unsigned*)&pa;
            pau[0] = pk_bf2(p[2 * h2][0], p[2 * h2][1]);
            pau[1] = pk_bf2(p[2 * h2][2], p[2 * h2][3]);
            pau[2] = pk_bf2(p[2 * h2 + 1][0], p[2 * h2 + 1][1]);
            pau[3] = pk_bf2(p[2 * h2 + 1][2], p[2 * h2 + 1][3]);
            // denominators: D[q][*] = rowsum(P) with the SAME packed weights
            lacc = __builtin_amdgcn_mfma_f32_16x16x32_bf16(pa, vones, lacc,
                                                           0, 0, 0);
#pragma unroll
            for (int ctile = 0; ctile < 2; ++ctile) {
                const int cA = ctile * 16 + ln;
                short8 vb;
                unsigned* vbu = (unsigned*)&vb;
#pragma unroll
                for (int g = 0; g < 2; ++g) {
                    const int gr = h2 * 4 + g * 2 + (quad >> 1);
                    const int sg = gr ^ (ln & 7);
                    uint2 vv = *(const uint2*)
                        &Vs[buf][cA * 64 + sg * 8 + (quad & 1) * 4];
                    vbu[g * 2 + 0] = vv.x;
                    vbu[g * 2 + 1] = vv.y;
                }
                oacc[ctile] = __builtin_amdgcn_mfma_f32_16x16x32_bf16(
                    pa, vb, oacc[ctile], 0, 0, 0);
            }
        }

#pragma unroll
        for (int ct = 0; ct < 4; ++ct) kf[ct] = kfn[ct];
        __syncthreads();
    }

    float* Oz = Opart + (size_t)z * CIN * NV;
    float* Lz = Lpart + (size_t)z * NHEAD * NV;
    if (ln == 0) {
#pragma unroll
        for (int r = 0; r < 4; ++r)
            Lz[(size_t)h * NV + q0 + w * 16 + quad * 4 + r] = lacc[r];
    }
#pragma unroll
    for (int ctile = 0; ctile < 2; ++ctile)
        *(f32x4*)&Oz[(size_t)(h * HD + ctile * 16 + ln) * NV + q0 + w * 16 +
                     quad * 4] = oacc[ctile];
}

// ---------------------------------------------------------------------------
// Kernel 3: fused combine + output projection. Stages
//   Y[n][c] = (O0+O1)[c][n]/(l0+l1) + qf[c][n]  (bf16, LDS) then
//   out = Wo(fp32, inline-converted) @ Y + bo.
// grid (NV/64, 512/64), block 256.
// ---------------------------------------------------------------------------
__global__ __launch_bounds__(256) void out_fused(
    const float* __restrict__ x,
    const float* __restrict__ Opart, const float* __restrict__ Lpart,
    const float* __restrict__ wo, const float* __restrict__ bo,
    float* __restrict__ out)
{
    const int n0 = blockIdx.x * 64;
    const int m0 = blockIdx.y * 64;
    const int t = threadIdx.x;

    __shared__ unsigned short Ys[64][264];  // [n][c], pitch 264

    const float* O0 = Opart;
    const float* O1 = Opart + (size_t)CIN * NV;
    const float* L0 = Lpart;
    const float* L1 = Lpart + (size_t)NHEAD * NV;

    {
        const int n = t & 63, cg = t >> 6;
#pragma unroll 4
        for (int cc = 0; cc < 64; cc += 2) {
            const int c = cg * 64 + cc;
            const int h = c >> 5;
            size_t off = (size_t)c * NV + n0 + n;
            size_t loff = (size_t)h * NV + n0 + n;
            float rl = __builtin_amdgcn_rcpf(L0[loff] + L1[loff]);
            float y0 = (O0[off] + O1[off]) * rl + x[off];
            float y1 = (O0[off + NV] + O1[off + NV]) * rl + x[off + NV];
            *(unsigned*)&Ys[n][c] = pk_bf2(y0, y1);
        }
    }
    __syncthreads();

    const int w = t >> 6;
    const int lane = t & 63;
    const int ln = lane & 15;
    const int quad = lane >> 4;
    const int M = m0 + w * 16 + ln;

    f32x4 acc[4] = {};
    for (int k0 = 0; k0 < 256; k0 += 32) {
        float4 a0 = *(const float4*)&wo[(size_t)M * 256 + k0 + quad * 8];
        float4 a1 = *(const float4*)&wo[(size_t)M * 256 + k0 + quad * 8 + 4];
        short8 a;
        unsigned* au = (unsigned*)&a;
        au[0] = pk_bf2(a0.x, a0.y);
        au[1] = pk_bf2(a0.z, a0.w);
        au[2] = pk_bf2(a1.x, a1.y);
        au[3] = pk_bf2(a1.z, a1.w);
        short8 b[4];
#pragma unroll
        for (int nt = 0; nt < 4; ++nt)
            b[nt] = *(const short8*)&Ys[nt * 16 + ln][k0 + quad * 8];
#pragma unroll
        for (int nt = 0; nt < 4; ++nt)
            acc[nt] = __builtin_amdgcn_mfma_f32_16x16x32_bf16(a, b[nt], acc[nt],
                                                              0, 0, 0);
    }

    const int mb = m0 + w * 16 + quad * 4;
    float bias[4];
#pragma unroll
    for (int r = 0; r < 4; ++r) bias[r] = bo[mb + r];
#pragma unroll
    for (int nt = 0; nt < 4; ++nt)
#pragma unroll
        for (int r = 0; r < 4; ++r)
            out[(size_t)(mb + r) * NV + n0 + nt * 16 + ln] = acc[nt][r] + bias[r];
}

// ---------------------------------------------------------------------------
extern "C" void kernel_launch(void* const* d_in, const int* in_sizes, int n_in,
                              void* d_out, int out_size, void* d_ws,
                              size_t ws_size, hipStream_t stream)
{
    const float* x  = (const float*)d_in[0];
    const float* wq = (const float*)d_in[1];
    const float* bq = (const float*)d_in[2];
    const float* wk = (const float*)d_in[3];
    const float* bk = (const float*)d_in[4];
    const float* wv = (const float*)d_in[5];
    const float* bv = (const float*)d_in[6];
    const float* wo = (const float*)d_in[7];
    const float* bo = (const float*)d_in[8];
    float* out = (float*)d_out;

    unsigned short* Qbf = (unsigned short*)d_ws;             // 2MB
    unsigned short* Kbf = Qbf + (size_t)CIN * NV;            // 2MB
    unsigned short* Vbf = Kbf + (size_t)CIN * NV;            // 2MB
    float* Lpart = (float*)(Vbf + (size_t)CIN * NV);         // 0.25MB
    float* Opart = Lpart + 2 * (size_t)NHEAD * NV;           // 8MB
    // total ws: ~14.3MB (same footprint as round 4)

    qkv_fused<<<dim3(NV / 64, 4, 3), 256, 0, stream>>>(
        x, wq, bq, wk, bk, wv, bv, Qbf, Kbf, Vbf);
    attn_mfma<<<dim3(NV / 64, NHEAD, NSPLIT), 256, 0, stream>>>(
        Qbf, Kbf, Vbf, Opart, Lpart);
    out_fused<<<dim3(NV / 64, 512 / 64), 256, 0, stream>>>(
        x, Opart, Lpart, wo, bo, out);
}